// Round 12
// baseline (53.795 us; speedup 1.0000x reference)
//
#include <hip/hip_runtime.h>
#include <hip/hip_bf16.h>
#include <math.h>

#define NB 16384
#define ND 128
#define NH 512
#define NO 128
#define NE 8
#define NCH 16                // chunks of 32 h
#define EPSF 2.2204460492503131e-16f

using bf16x8 = __attribute__((ext_vector_type(8))) short;
using f32x16 = __attribute__((ext_vector_type(16))) float;
using uint2v = __attribute__((ext_vector_type(2))) unsigned;

// ---- workspace layout (bytes) ----
#define WS_BLKCNT 0u                       // int  [256][8]
#define WS_BLKIMP 8192u                    // float[256][8]
#define WS_TOKID  16384u                   // int  [NE][256*128] (tok | which<<30), per-block 128-slot regions
#define WS_TOKGG  1064960u                 // float2[NB]
#define WS_XBF    1196032u                 // ushort[NB][ND]
#define WS_W1F    5390336u                 // ushort frag-linear w1 (1MB)
#define WS_W2F    6438912u                 // ushort frag-linear w2 (1MB)

__device__ __forceinline__ unsigned f2bf(float f){
  unsigned u = __float_as_uint(f);
  u += 0x7FFFu + ((u >> 16) & 1u);
  return u >> 16;
}
__device__ __forceinline__ unsigned cvtpk(float lo, float hi){
  unsigned r;
  asm("v_cvt_pk_bf16_f32 %0, %1, %2" : "=v"(r) : "v"(lo), "v"(hi));
  return r;
}
__device__ __forceinline__ void gld16(const void* g, void* l){
  __builtin_amdgcn_global_load_lds((const __attribute__((address_space(1))) void*)g,
                                   (__attribute__((address_space(3))) void*)l, 16, 0, 0);
}

// ============ prep: gating + y-zero (blocks 0-255) + w1 pack (256-511) + w2 pack (512-767)
__global__ __launch_bounds__(256) void prep_kernel(
    const float* __restrict__ x, const float* __restrict__ wg,
    const float* __restrict__ w1, const float* __restrict__ w2,
    unsigned short* __restrict__ xbf, unsigned short* __restrict__ w1f,
    unsigned short* __restrict__ w2f, int* __restrict__ blk_cnt,
    float* __restrict__ blk_imp, int* __restrict__ tok_ids, float2* __restrict__ tok_gg,
    float* __restrict__ y){
  int bx = blockIdx.x, tid = threadIdx.x;
  if (bx >= 512){            // ---- w2 pack: w2f[e][c32(16)][hb(4)][o(128)][8h]
    int u = (bx - 512)*256 + tid;
    int o = u & 127, hb = (u>>7)&3, c = (u>>9)&15, e = u>>13;
    int h0 = c*32 + (hb>>1)*16 + (hb&1)*8;
    const float* src = w2 + (size_t)e*NH*NO + (size_t)h0*NO + o;
    unsigned q[4];
    #pragma unroll
    for (int p = 0; p < 4; ++p)
      q[p] = f2bf(src[(2*p)*NO]) | (f2bf(src[(2*p+1)*NO]) << 16);
    *(uint4*)(w2f + (size_t)u*8) = make_uint4(q[0], q[1], q[2], q[3]);
    return;
  }
  if (bx >= 256){            // ---- w1 pack: w1f[e][c32(16)][db(16)][h32(32)][8d]
    int u = (bx - 256)*256 + tid;
    int h32 = u & 31, db = (u>>5)&15, c = (u>>9)&15, e = u>>13;
    int d0 = (db>>1)*16 + (db&1)*8;
    int hg = c*32 + h32;
    const float* src = w1 + (size_t)e*ND*NH + (size_t)d0*NH + hg;
    unsigned q[4];
    #pragma unroll
    for (int p = 0; p < 4; ++p)
      q[p] = f2bf(src[(2*p)*NH]) | (f2bf(src[(2*p+1)*NH]) << 16);
    *(uint4*)(w1f + (size_t)u*8) = make_uint4(q[0], q[1], q[2], q[3]);
    return;
  }
  // ---- zero this block's 64 y rows (expert accumulates atomically; no combine pass)
  {
    float4 z = {0.f, 0.f, 0.f, 0.f};
    float* yb = y + (size_t)bx*64*NO + tid*32;   // 256 thr x 32 f32 = 8192 f32
    #pragma unroll
    for (int i = 0; i < 8; ++i) *(float4*)(yb + i*4) = z;
    if (bx == 0 && tid == 0) y[NB*NO] = 0.f;
  }
  // ---- gating: 64 tokens/block, 4 lanes/token, f64 logits
  __shared__ int   lcnt[NE];
  __shared__ float limp[NE];
  if (tid < NE){ lcnt[tid] = 0; limp[tid] = 0.f; }
  __syncthreads();
  int tok  = bx*64 + (tid >> 2);
  int part = tid & 3;
  const float4* xr4 = (const float4*)(x + (size_t)tok*ND);
  double acc[NE];
  #pragma unroll
  for (int e = 0; e < NE; ++e) acc[e] = 0.0;
  #pragma unroll
  for (int j = 0; j < 8; ++j){
    int f4 = part + j*4;
    float4 v = xr4[f4];
    uint2 p;
    p.x = f2bf(v.x) | (f2bf(v.y) << 16);
    p.y = f2bf(v.z) | (f2bf(v.w) << 16);
    *(uint2*)(xbf + (size_t)tok*ND + f4*4) = p;
    const float4* wr = (const float4*)(wg + f4*32);
    float vm[4] = {v.x, v.y, v.z, v.w};
    #pragma unroll
    for (int m = 0; m < 4; ++m){
      float4 wa = wr[2*m], wb = wr[2*m+1];
      double d = (double)vm[m];
      acc[0] += d*(double)wa.x; acc[1] += d*(double)wa.y;
      acc[2] += d*(double)wa.z; acc[3] += d*(double)wa.w;
      acc[4] += d*(double)wb.x; acc[5] += d*(double)wb.y;
      acc[6] += d*(double)wb.z; acc[7] += d*(double)wb.w;
    }
  }
  #pragma unroll
  for (int e = 0; e < NE; ++e){
    acc[e] += __shfl_xor(acc[e], 1);
    acc[e] += __shfl_xor(acc[e], 2);
  }
  if (part == 0){
    int i0 = 0;
    double l0 = acc[0];
    #pragma unroll
    for (int e = 1; e < NE; ++e) if (acc[e] > l0){ l0 = acc[e]; i0 = e; }
    int i1 = (i0 == 0) ? 1 : 0;
    double l1 = acc[i1];
    #pragma unroll
    for (int e = 0; e < NE; ++e) if (e != i0 && acc[e] > l1){ l1 = acc[e]; i1 = e; }
    float e1 = expf((float)(l1 - l0));
    float g0 = 1.0f/(1.0f + e1);
    float g1 = e1/(1.0f + e1);
    int s0 = atomicAdd(&lcnt[i0], 1);
    int s1 = atomicAdd(&lcnt[i1], 1);
    atomicAdd(&limp[i0], g0);
    atomicAdd(&limp[i1], g1);
    tok_gg[tok] = make_float2(g0, g1);
    tok_ids[i0*32768 + bx*128 + s0] = tok;                 // per-block 128-slot region
    tok_ids[i1*32768 + bx*128 + s1] = tok | (1 << 30);
  }
  __syncthreads();
  if (tid < NE){
    blk_cnt[bx*8 + tid] = lcnt[tid];
    blk_imp[bx*8 + tid] = limp[tid];
  }
}

// ============ experts: R6/R11 core + LDS scan; epilogue = gate-scaled f32 atomicAdd into y.
// Block 0 additionally computes the loss (imp reduce + totl from scan) -> y[NB*NO].
__global__ __launch_bounds__(256) void expert_kernel(
    const unsigned short* __restrict__ xbf, const unsigned short* __restrict__ w1f,
    const unsigned short* __restrict__ w2f, const float* __restrict__ b1,
    const float* __restrict__ b2, const int* __restrict__ blk_cnt,
    const float* __restrict__ blk_imp, const int* __restrict__ tok_ids,
    const float2* __restrict__ tok_gg, float* __restrict__ y){
  __shared__ char L[44032];            // wbuf 32K | cnt_l 8K | gp 1K | totl/tbase/sl_tok/simp
  int* cnt_l  = (int*)(L + 32768);     // [e][256 blocks]
  int* gp     = (int*)(L + 40960);     // [e][32] inclusive group prefixes
  int* totl   = (int*)(L + 41984);     // [8]
  int* tbase  = (int*)(L + 42016);     // [9]
  int* sl_tok = (int*)(L + 42056);     // [128]
  float* simp = (float*)(L + 42568);   // [32]
  int tid = threadIdx.x;
  { // load + transpose count matrix
    int4 a = *(const int4*)(blk_cnt + tid*8);
    int4 c = *(const int4*)(blk_cnt + tid*8 + 4);
    cnt_l[0*256+tid]=a.x; cnt_l[1*256+tid]=a.y; cnt_l[2*256+tid]=a.z; cnt_l[3*256+tid]=a.w;
    cnt_l[4*256+tid]=c.x; cnt_l[5*256+tid]=c.y; cnt_l[6*256+tid]=c.z; cnt_l[7*256+tid]=c.w;
  }
  __syncthreads();
  { // group-8 sums + scan over 32 groups per expert
    int e8 = tid >> 5, g8 = tid & 31;
    int s8 = 0;
    #pragma unroll
    for (int i = 0; i < 8; ++i) s8 += cnt_l[e8*256 + g8*8 + i];
    gp[tid] = s8;
    __syncthreads();
    #pragma unroll
    for (int st = 1; st < 32; st <<= 1){
      int add = (g8 >= st) ? gp[tid - st] : 0;
      __syncthreads();
      gp[tid] += add;
      __syncthreads();
    }
    if (g8 == 31) totl[e8] = gp[tid];
    __syncthreads();
    if (tid == 0){
      tbase[0] = 0;
      #pragma unroll
      for (int e = 0; e < NE; ++e) tbase[e+1] = tbase[e] + ((totl[e] + 127) >> 7);
    }
    __syncthreads();
  }
  int b = blockIdx.x;
  if (b >= tbase[8]) return;
  // ---- block 0: loss (importance totals from blk_imp, load totals from totl)
  if (b == 0){
    int lane = tid & 63, wv = tid >> 6;
    float4 ia = *(const float4*)(blk_imp + tid*8);
    float4 ib = *(const float4*)(blk_imp + tid*8 + 4);
    float iv[8] = {ia.x, ia.y, ia.z, ia.w, ib.x, ib.y, ib.z, ib.w};
    #pragma unroll
    for (int e2 = 0; e2 < NE; ++e2){
      float ri = iv[e2];
      #pragma unroll
      for (int st = 1; st < 64; st <<= 1) ri += __shfl_xor(ri, st);
      if (lane == 0) simp[e2*4 + wv] = ri;
    }
    __syncthreads();
    if (tid == 0){
      double si = 0, sqi = 0, sl = 0, sql = 0;
      #pragma unroll
      for (int e2 = 0; e2 < NE; ++e2){
        double a = (double)(simp[e2*4] + simp[e2*4+1] + simp[e2*4+2] + simp[e2*4+3]);
        double bb = (double)totl[e2];
        si += a; sqi += a*a; sl += bb; sql += bb*bb;
      }
      double mi = si/8.0, vi = (sqi - 8.0*mi*mi)/7.0;
      double ml = sl/8.0, vl = (sql - 8.0*ml*ml)/7.0;
      y[NB*NO] = (float)(vi/(mi*mi + 1e-10) + vl/(ml*ml + 1e-10));
    }
  }
  int e = 0;
  #pragma unroll
  for (int ee = 1; ee < NE; ++ee) if (tbase[ee] <= b) e = ee;
  int n_e  = totl[e];
  int base = (b - tbase[e])*128;
  if (tid < 128){                       // resolve 128 slots -> token ids
    int s = base + tid;
    if (s >= n_e) s = n_e - 1;
    int g = 0;
    #pragma unroll
    for (int st = 16; st; st >>= 1){
      int c = g + st;
      if (c <= 31 && gp[e*32 + c - 1] <= s) g = c;
    }
    int acc2 = g ? gp[e*32 + g - 1] : 0;
    int gb = g*8;
    while (true){
      int c2 = cnt_l[e*256 + gb];
      if (acc2 + c2 > s) break;
      acc2 += c2; ++gb;
    }
    sl_tok[tid] = tok_ids[e*32768 + gb*128 + (s - acc2)];
  }
  __syncthreads();

  int wid = tid >> 6, lane = tid & 63, l31 = lane & 31, hi = lane >> 5;
  char* w1buf = L;                      // [2][8192]
  char* w2buf = L + 16384;              // [2][8192]
  const char* g1base = (const char*)w1f + (size_t)e*131072;
  const char* g2base = (const char*)w2f + (size_t)e*131072;

  int raw0 = sl_tok[wid*32 + l31];
  int tok0 = raw0 & 0x3FFFFFFF;
  bf16x8 xfrag[8];
  #pragma unroll
  for (int k = 0; k < 8; ++k)
    xfrag[k] = *(const bf16x8*)(xbf + (size_t)tok0*ND + (k*2 + hi)*8);

#define STAGE(c, bsel) do { \
    const char* _g1 = g1base + (size_t)(c)*8192 + wid*1024 + lane*16; \
    const char* _g2 = g2base + (size_t)(c)*8192 + wid*1024 + lane*16; \
    char* _l1 = w1buf + (bsel)*8192 + wid*1024; \
    char* _l2 = w2buf + (bsel)*8192 + wid*1024; \
    _Pragma("unroll") \
    for (int _s = 0; _s < 2; ++_s){ \
      gld16(_g1 + _s*4096, _l1 + _s*4096); \
      gld16(_g2 + _s*4096, _l2 + _s*4096); \
    } \
  } while(0)

  STAGE(0, 0);
  f32x16 yacc[4];
  #pragma unroll
  for (int ot = 0; ot < 4; ++ot)
    #pragma unroll
    for (int i = 0; i < 16; ++i) yacc[ot][i] = 0.f;
  __syncthreads();

  for (int c = 0; c < NCH; ++c){
    int bb = c & 1;
    if (c + 1 < NCH) STAGE(c + 1, bb ^ 1);
    f32x16 hacc;
    #pragma unroll
    for (int i = 0; i < 16; ++i) hacc[i] = 0.f;
    #pragma unroll
    for (int k = 0; k < 8; ++k){
      bf16x8 a = *(const bf16x8*)(w1buf + bb*8192 + (k*2 + hi)*512 + l31*16);
      hacc = __builtin_amdgcn_mfma_f32_32x32x16_bf16(a, xfrag[k], hacc, 0, 0, 0);
    }
    const float4* b1p = (const float4*)(b1 + e*NH + c*32 + hi*4);
    float dv[16];
    #pragma unroll
    for (int g = 0; g < 4; ++g){
      float4 bv = b1p[2*g];
      dv[4*g+0] = fmaxf(hacc[4*g+0] + bv.x, 0.f);
      dv[4*g+1] = fmaxf(hacc[4*g+1] + bv.y, 0.f);
      dv[4*g+2] = fmaxf(hacc[4*g+2] + bv.z, 0.f);
      dv[4*g+3] = fmaxf(hacc[4*g+3] + bv.w, 0.f);
    }
    unsigned A0 = cvtpk(dv[0], dv[1]),   A1 = cvtpk(dv[2], dv[3]);
    unsigned A2 = cvtpk(dv[4], dv[5]),   A3 = cvtpk(dv[6], dv[7]);
    unsigned A4 = cvtpk(dv[8], dv[9]),   A5 = cvtpk(dv[10], dv[11]);
    unsigned A6 = cvtpk(dv[12], dv[13]), A7 = cvtpk(dv[14], dv[15]);
    uint2v r0 = __builtin_amdgcn_permlane32_swap(A0, A2, false, false);
    uint2v r1 = __builtin_amdgcn_permlane32_swap(A1, A3, false, false);
    uint2v r2 = __builtin_amdgcn_permlane32_swap(A4, A6, false, false);
    uint2v r3 = __builtin_amdgcn_permlane32_swap(A5, A7, false, false);
    union { unsigned u[4]; bf16x8 v; } fa, fb;
    fa.u[0] = r0[0]; fa.u[1] = r1[0]; fa.u[2] = r0[1]; fa.u[3] = r1[1];
    fb.u[0] = r2[0]; fb.u[1] = r3[0]; fb.u[2] = r2[1]; fb.u[3] = r3[1];
    bf16x8 aht0 = fa.v, aht1 = fb.v;
    #pragma unroll
    for (int ot = 0; ot < 4; ++ot){
      bf16x8 bf0 = *(const bf16x8*)(w2buf + bb*8192 + hi*2048 + (ot*32 + l31)*16);
      yacc[ot] = __builtin_amdgcn_mfma_f32_32x32x16_bf16(aht0, bf0, yacc[ot], 0, 0, 0);
      bf16x8 bf1 = *(const bf16x8*)(w2buf + bb*8192 + (2 + hi)*2048 + (ot*32 + l31)*16);
      yacc[ot] = __builtin_amdgcn_mfma_f32_32x32x16_bf16(aht1, bf1, yacc[ot], 0, 0, 0);
    }
    __syncthreads();
  }
#undef STAGE
  float b2v[4];
  #pragma unroll
  for (int ot = 0; ot < 4; ++ot) b2v[ot] = b2[e*NO + ot*32 + l31];
  #pragma unroll
  for (int r = 0; r < 16; ++r){
    int row = (r & 3) + 8*(r >> 2) + 4*hi;
    int slot = base + wid*32 + row;
    if (slot < n_e){
      int rw = sl_tok[wid*32 + row];
      int tk = rw & 0x3FFFFFFF, wh = (rw >> 30) & 1;
      float2 gg = tok_gg[tk];
      float g = wh ? gg.y : gg.x;
      float* yrow = y + (size_t)tk*NO + l31;
      #pragma unroll
      for (int ot = 0; ot < 4; ++ot)
        atomicAdd(yrow + ot*32, (yacc[ot][r] + b2v[ot]) * g);
    }
  }
}

extern "C" void kernel_launch(void* const* d_in, const int* in_sizes, int n_in,
                              void* d_out, int out_size, void* d_ws, size_t ws_size,
                              hipStream_t stream){
  (void)in_sizes; (void)n_in; (void)out_size; (void)ws_size;
  const float* x  = (const float*)d_in[0];
  const float* wg = (const float*)d_in[1];
  const float* w1 = (const float*)d_in[2];
  const float* b1 = (const float*)d_in[3];
  const float* w2 = (const float*)d_in[4];
  const float* b2 = (const float*)d_in[5];
  float* out = (float*)d_out;
  char* ws = (char*)d_ws;
  int*            blk_cnt = (int*)(ws + WS_BLKCNT);
  float*          blk_imp = (float*)(ws + WS_BLKIMP);
  int*            tok_ids = (int*)(ws + WS_TOKID);
  float2*         tok_gg  = (float2*)(ws + WS_TOKGG);
  unsigned short* xbf     = (unsigned short*)(ws + WS_XBF);
  unsigned short* w1f     = (unsigned short*)(ws + WS_W1F);
  unsigned short* w2f     = (unsigned short*)(ws + WS_W2F);

  prep_kernel<<<768, 256, 0, stream>>>(x, wg, w1, w2, xbf, w1f, w2f,
                                       blk_cnt, blk_imp, tok_ids, tok_gg, out);
  expert_kernel<<<264, 256, 0, stream>>>(xbf, w1f, w2f, b1, b2,
                                         blk_cnt, blk_imp, tok_ids, tok_gg, out);
}